// Round 1
// baseline (381.448 us; speedup 1.0000x reference)
//
#include <hip/hip_runtime.h>
#include <cstdint>

#define FLT_MAX_ 3.402823466e+38f

// ---------------------------------------------------------------------------
// Pass 0: codebook squared norms ee[k] = ||cb_k||^2   (K=1024, D=256)
// One wave per code: 64 lanes x float4 = 256 elements.
// ---------------------------------------------------------------------------
__global__ __launch_bounds__(256) void vq_code_norms(const float* __restrict__ cb,
                                                     float* __restrict__ ee, int K) {
  int wave = threadIdx.x >> 6, lane = threadIdx.x & 63;
  int k = blockIdx.x * 4 + wave;
  if (k >= K) return;
  float4 v = *reinterpret_cast<const float4*>(cb + (size_t)k * 256 + lane * 4);
  float s = v.x * v.x + v.y * v.y + v.z * v.z + v.w * v.w;
  #pragma unroll
  for (int off = 32; off; off >>= 1) s += __shfl_down(s, off, 64);
  if (lane == 0) ee[k] = s;
}

// ---------------------------------------------------------------------------
// Pass 1: fused distance-GEMM + argmin.
// score(n,k) = ||e_k||^2 - 2 * z_n . e_k   (||z||^2 constant per token -> dropped)
// Block: 256 thr viewed as 16x16 (tx = code dim, ty = token dim).
// Block tile: 128 tokens x 128 codes per K-chunk; thread tile 8x8 with
// interleaved assignment (tokens ty+16i, codes tx+16j).
// LDS: 128x64-float chunks of z and cb, float4-XOR-swizzled (q' = q ^ (row&15))
// so both compute reads and staging writes are bank-conflict-free b128 ops.
// Exactly 64 KB static LDS -> 2 blocks/CU.
// ---------------------------------------------------------------------------
__global__ __launch_bounds__(256, 2) void vq_argmin(
    const float* __restrict__ z, const float* __restrict__ cb,
    const float* __restrict__ ee, int* __restrict__ out_idx, int K) {
  __shared__ float zs[128 * 64];
  __shared__ float cs[128 * 64];
  const int t = threadIdx.x;
  const int tx = t & 15, ty = t >> 4;
  const int m0 = blockIdx.x * 128;

  float best[8];
  int bidx[8];
  #pragma unroll
  for (int i = 0; i < 8; ++i) { best[i] = FLT_MAX_; bidx[i] = 0; }

  const int nkc = K >> 7;
  for (int kc = 0; kc < nkc; ++kc) {
    float acc[8][8];
    #pragma unroll
    for (int i = 0; i < 8; ++i)
      #pragma unroll
      for (int j = 0; j < 8; ++j) acc[i][j] = 0.0f;

    for (int dc = 0; dc < 4; ++dc) {
      __syncthreads();  // protect previous chunk's readers before overwrite
      // Cooperative stage: 128 rows x 64 floats each of z-tile and cb-chunk.
      // 16 consecutive lanes read one 256 B row segment -> fully coalesced.
      #pragma unroll
      for (int i = 0; i < 8; ++i) {
        int row = (t >> 4) + 16 * i;      // 0..127
        int q   = t & 15;                 // float4 slot within row
        int sw  = q ^ (row & 15);         // XOR swizzle
        float4 v = *reinterpret_cast<const float4*>(
            z + (size_t)(m0 + row) * 256 + dc * 64 + q * 4);
        *reinterpret_cast<float4*>(&zs[row * 64 + sw * 4]) = v;
        float4 w = *reinterpret_cast<const float4*>(
            cb + (size_t)(kc * 128 + row) * 256 + dc * 64 + q * 4);
        *reinterpret_cast<float4*>(&cs[row * 64 + sw * 4]) = w;
      }
      __syncthreads();
      #pragma unroll 2
      for (int q = 0; q < 16; ++q) {
        float4 za[8], ca[8];
        #pragma unroll
        for (int i = 0; i < 8; ++i)
          za[i] = *reinterpret_cast<const float4*>(
              &zs[(ty + 16 * i) * 64 + ((q ^ ty) * 4)]);
        #pragma unroll
        for (int j = 0; j < 8; ++j)
          ca[j] = *reinterpret_cast<const float4*>(
              &cs[(tx + 16 * j) * 64 + ((q ^ tx) * 4)]);
        #pragma unroll
        for (int i = 0; i < 8; ++i) {
          #pragma unroll
          for (int j = 0; j < 8; ++j) {
            acc[i][j] = fmaf(za[i].x, ca[j].x, acc[i][j]);
            acc[i][j] = fmaf(za[i].y, ca[j].y, acc[i][j]);
            acc[i][j] = fmaf(za[i].z, ca[j].z, acc[i][j]);
            acc[i][j] = fmaf(za[i].w, ca[j].w, acc[i][j]);
          }
        }
      }
    }
    // Min update for this K-chunk (ascending k within thread -> first-min tie-break)
    #pragma unroll
    for (int j = 0; j < 8; ++j) {
      int k = (kc << 7) + tx + 16 * j;
      float e = ee[k];
      #pragma unroll
      for (int i = 0; i < 8; ++i) {
        float s = fmaf(-2.0f, acc[i][j], e);
        if (s < best[i] || (s == best[i] && k < bidx[i])) { best[i] = s; bidx[i] = k; }
      }
    }
  }
  // Reduce across the 16 tx lanes (a same-ty group is 16 consecutive lanes).
  #pragma unroll
  for (int off = 8; off; off >>= 1) {
    #pragma unroll
    for (int i = 0; i < 8; ++i) {
      float os = __shfl_xor(best[i], off, 64);
      int   oi = __shfl_xor(bidx[i], off, 64);
      if (os < best[i] || (os == best[i] && oi < bidx[i])) { best[i] = os; bidx[i] = oi; }
    }
  }
  if (tx == 0) {
    #pragma unroll
    for (int i = 0; i < 8; ++i) out_idx[m0 + ty + 16 * i] = bidx[i];
  }
}

// ---------------------------------------------------------------------------
// Pass 2: gather cb[idx], write quantized = q*m and indices (as float),
// accumulate Sum(m*||z-q||^2) and Sum(m). One wave per token, 128 tokens/block,
// one atomic pair per block (256 blocks -> negligible contention).
// ---------------------------------------------------------------------------
__global__ __launch_bounds__(256) void vq_finalize(
    const float* __restrict__ z, const float* __restrict__ cb,
    const float* __restrict__ mask, const int* __restrict__ idxs,
    float* __restrict__ out_q, float* __restrict__ out_idx_f,
    float* __restrict__ acc2) {
  __shared__ float red[8];
  const int lane = threadIdx.x & 63, wave = threadIdx.x >> 6;
  const int base = blockIdx.x * 128;
  float lsum = 0.f, msum = 0.f;
  for (int it = 0; it < 32; ++it) {
    int n = base + it * 4 + wave;
    float m = mask[n];
    int k = idxs[n];
    float4 zv = *reinterpret_cast<const float4*>(z + (size_t)n * 256 + lane * 4);
    float4 qv = *reinterpret_cast<const float4*>(cb + (size_t)k * 256 + lane * 4);
    float4 o;
    o.x = qv.x * m; o.y = qv.y * m; o.z = qv.z * m; o.w = qv.w * m;
    *reinterpret_cast<float4*>(out_q + (size_t)n * 256 + lane * 4) = o;
    float dx = zv.x - qv.x, dy = zv.y - qv.y, dz = zv.z - qv.z, dw = zv.w - qv.w;
    lsum = fmaf(m, dx * dx + dy * dy + dz * dz + dw * dw, lsum);
    if (lane == 0) {
      msum += m;
      out_idx_f[n] = (m > 0.f) ? (float)k : 0.f;
    }
  }
  #pragma unroll
  for (int off = 32; off; off >>= 1) lsum += __shfl_down(lsum, off, 64);
  if (lane == 0) { red[wave] = lsum; red[4 + wave] = msum; }
  __syncthreads();
  if (threadIdx.x == 0) {
    atomicAdd(&acc2[0], red[0] + red[1] + red[2] + red[3]);
    atomicAdd(&acc2[1], red[4] + red[5] + red[6] + red[7]);
  }
}

// Pass 3: loss = 0.25 * S / (n_valid * D)
__global__ void vq_loss_final(const float* __restrict__ acc2,
                              float* __restrict__ out_loss) {
  if (threadIdx.x == 0 && blockIdx.x == 0) {
    float nv = acc2[1];
    out_loss[0] = (nv > 0.f) ? (0.25f * acc2[0] / (nv * 256.0f)) : 0.0f;
  }
}

// ---------------------------------------------------------------------------
extern "C" void kernel_launch(void* const* d_in, const int* in_sizes, int n_in,
                              void* d_out, int out_size, void* d_ws, size_t ws_size,
                              hipStream_t stream) {
  const float* z    = (const float*)d_in[0];  // (N, 256)
  const float* mask = (const float*)d_in[1];  // (N,)
  const float* cb   = (const float*)d_in[2];  // (K, 256)
  const int N = in_sizes[1];                  // 32768
  const int D = 256;
  const int K = in_sizes[2] / D;              // 1024

  float* ws    = (float*)d_ws;
  float* acc2  = ws;                          // [0]=loss sum, [1]=n_valid
  float* ee    = ws + 8;                      // K floats
  int*   idxs  = (int*)(ws + 8 + K);          // N ints

  float* out_q      = (float*)d_out;          // N*D floats
  float* out_loss   = out_q + (size_t)N * D;  // 1 float
  float* out_idx_f  = out_loss + 1;           // N floats (indices as f32)

  hipMemsetAsync(acc2, 0, 2 * sizeof(float), stream);
  vq_code_norms<<<(K + 3) / 4, 256, 0, stream>>>(cb, ee, K);
  vq_argmin<<<N / 128, 256, 0, stream>>>(z, cb, ee, idxs, K);
  vq_finalize<<<N / 128, 256, 0, stream>>>(z, cb, mask, idxs, out_q, out_idx_f, acc2);
  vq_loss_final<<<1, 64, 0, stream>>>(acc2, out_loss);
}

// Round 2
// 343.337 us; speedup vs baseline: 1.1110x; 1.1110x over previous
//
#include <hip/hip_runtime.h>
#include <cstdint>

#define FLT_MAX_ 3.402823466e+38f

// ---------------------------------------------------------------------------
// Pass 0: codebook squared norms ee[k] = ||cb_k||^2   (K=1024, D=256)
// ---------------------------------------------------------------------------
__global__ __launch_bounds__(256) void vq_code_norms(const float* __restrict__ cb,
                                                     float* __restrict__ ee, int K) {
  int wave = threadIdx.x >> 6, lane = threadIdx.x & 63;
  int k = blockIdx.x * 4 + wave;
  if (k >= K) return;
  float4 v = *reinterpret_cast<const float4*>(cb + (size_t)k * 256 + lane * 4);
  float s = v.x * v.x + v.y * v.y + v.z * v.z + v.w * v.w;
  #pragma unroll
  for (int off = 32; off; off >>= 1) s += __shfl_down(s, off, 64);
  if (lane == 0) ee[k] = s;
}

// ---------------------------------------------------------------------------
// Pass 1: fused distance-GEMM + argmin, K-SPLIT x2 for occupancy.
// Grid = (N/128 token tiles) x 2 code-halves = 512 blocks -> 2 blocks/CU
// (R1 post-mortem: 256 blocks = 1 wave/SIMD gave VALUBusy 49%; latency-bound).
// Each block: 128 tokens x 512 codes, score = ||e||^2 - 2 z.e.
// Partial (best,idx) per (token, half) merged in vq_finalize.
// LDS 64 KB static -> exactly 2 blocks/CU (128/160 KB).
// ---------------------------------------------------------------------------
__global__ __launch_bounds__(256, 2) void vq_argmin(
    const float* __restrict__ z, const float* __restrict__ cb,
    const float* __restrict__ ee, float* __restrict__ pbest,
    int* __restrict__ pidx, int K) {
  __shared__ float zs[128 * 64];
  __shared__ float cs[128 * 64];
  const int t = threadIdx.x;
  const int tx = t & 15, ty = t >> 4;
  const int m0 = (blockIdx.x >> 1) * 128;
  const int half = blockIdx.x & 1;
  const int kbase = half * (K >> 1);

  float best[8];
  int bidx[8];
  #pragma unroll
  for (int i = 0; i < 8; ++i) { best[i] = FLT_MAX_; bidx[i] = 0; }

  const int nkc = K >> 8;  // chunks of 128 codes within this half
  for (int kc = 0; kc < nkc; ++kc) {
    float acc[8][8];
    #pragma unroll
    for (int i = 0; i < 8; ++i)
      #pragma unroll
      for (int j = 0; j < 8; ++j) acc[i][j] = 0.0f;

    for (int dc = 0; dc < 4; ++dc) {
      __syncthreads();
      #pragma unroll
      for (int i = 0; i < 8; ++i) {
        int row = (t >> 4) + 16 * i;
        int q   = t & 15;
        int sw  = q ^ (row & 15);
        float4 v = *reinterpret_cast<const float4*>(
            z + (size_t)(m0 + row) * 256 + dc * 64 + q * 4);
        *reinterpret_cast<float4*>(&zs[row * 64 + sw * 4]) = v;
        float4 w = *reinterpret_cast<const float4*>(
            cb + (size_t)(kbase + kc * 128 + row) * 256 + dc * 64 + q * 4);
        *reinterpret_cast<float4*>(&cs[row * 64 + sw * 4]) = w;
      }
      __syncthreads();
      #pragma unroll 2
      for (int q = 0; q < 16; ++q) {
        float4 za[8], ca[8];
        #pragma unroll
        for (int i = 0; i < 8; ++i)
          za[i] = *reinterpret_cast<const float4*>(
              &zs[(ty + 16 * i) * 64 + ((q ^ ty) * 4)]);
        #pragma unroll
        for (int j = 0; j < 8; ++j)
          ca[j] = *reinterpret_cast<const float4*>(
              &cs[(tx + 16 * j) * 64 + ((q ^ tx) * 4)]);
        #pragma unroll
        for (int i = 0; i < 8; ++i) {
          #pragma unroll
          for (int j = 0; j < 8; ++j) {
            acc[i][j] = fmaf(za[i].x, ca[j].x, acc[i][j]);
            acc[i][j] = fmaf(za[i].y, ca[j].y, acc[i][j]);
            acc[i][j] = fmaf(za[i].z, ca[j].z, acc[i][j]);
            acc[i][j] = fmaf(za[i].w, ca[j].w, acc[i][j]);
          }
        }
      }
    }
    #pragma unroll
    for (int j = 0; j < 8; ++j) {
      int k = kbase + (kc << 7) + tx + 16 * j;
      float e = ee[k];
      #pragma unroll
      for (int i = 0; i < 8; ++i) {
        float s = fmaf(-2.0f, acc[i][j], e);
        if (s < best[i] || (s == best[i] && k < bidx[i])) { best[i] = s; bidx[i] = k; }
      }
    }
  }
  #pragma unroll
  for (int off = 8; off; off >>= 1) {
    #pragma unroll
    for (int i = 0; i < 8; ++i) {
      float os = __shfl_xor(best[i], off, 64);
      int   oi = __shfl_xor(bidx[i], off, 64);
      if (os < best[i] || (os == best[i] && oi < bidx[i])) { best[i] = os; bidx[i] = oi; }
    }
  }
  if (tx == 0) {
    #pragma unroll
    for (int i = 0; i < 8; ++i) {
      int n = m0 + ty + 16 * i;
      pbest[2 * n + half] = best[i];
      pidx [2 * n + half] = bidx[i];
    }
  }
}

// ---------------------------------------------------------------------------
// Pass 2: merge the 2 K-split partials, gather cb[idx], write quantized = q*m
// and indices (as float), accumulate Sum(m*||z-q||^2) and Sum(m).
// Tie-break: strict < picks half 0 (lower k range) on ties -> matches argmin.
// ---------------------------------------------------------------------------
__global__ __launch_bounds__(256) void vq_finalize(
    const float* __restrict__ z, const float* __restrict__ cb,
    const float* __restrict__ mask, const float* __restrict__ pbest,
    const int* __restrict__ pidx,
    float* __restrict__ out_q, float* __restrict__ out_idx_f,
    float* __restrict__ acc2) {
  __shared__ float red[8];
  const int lane = threadIdx.x & 63, wave = threadIdx.x >> 6;
  const int base = blockIdx.x * 128;
  float lsum = 0.f, msum = 0.f;
  for (int it = 0; it < 32; ++it) {
    int n = base + it * 4 + wave;
    float m = mask[n];
    float b0 = pbest[2 * n], b1 = pbest[2 * n + 1];
    int k = (b1 < b0) ? pidx[2 * n + 1] : pidx[2 * n];
    float4 zv = *reinterpret_cast<const float4*>(z + (size_t)n * 256 + lane * 4);
    float4 qv = *reinterpret_cast<const float4*>(cb + (size_t)k * 256 + lane * 4);
    float4 o;
    o.x = qv.x * m; o.y = qv.y * m; o.z = qv.z * m; o.w = qv.w * m;
    *reinterpret_cast<float4*>(out_q + (size_t)n * 256 + lane * 4) = o;
    float dx = zv.x - qv.x, dy = zv.y - qv.y, dz = zv.z - qv.z, dw = zv.w - qv.w;
    lsum = fmaf(m, dx * dx + dy * dy + dz * dz + dw * dw, lsum);
    if (lane == 0) {
      msum += m;
      out_idx_f[n] = (m > 0.f) ? (float)k : 0.f;
    }
  }
  #pragma unroll
  for (int off = 32; off; off >>= 1) lsum += __shfl_down(lsum, off, 64);
  if (lane == 0) { red[wave] = lsum; red[4 + wave] = msum; }
  __syncthreads();
  if (threadIdx.x == 0) {
    atomicAdd(&acc2[0], red[0] + red[1] + red[2] + red[3]);
    atomicAdd(&acc2[1], red[4] + red[5] + red[6] + red[7]);
  }
}

// Pass 3: loss = 0.25 * sum / (n_valid * D)
__global__ void vq_loss_final(const float* __restrict__ acc2,
                              float* __restrict__ out_loss) {
  if (threadIdx.x == 0 && blockIdx.x == 0) {
    float nv = acc2[1];
    out_loss[0] = (nv > 0.f) ? (0.25f * acc2[0] / (nv * 256.0f)) : 0.0f;
  }
}

// ---------------------------------------------------------------------------
extern "C" void kernel_launch(void* const* d_in, const int* in_sizes, int n_in,
                              void* d_out, int out_size, void* d_ws, size_t ws_size,
                              hipStream_t stream) {
  const float* z    = (const float*)d_in[0];  // (N, 256)
  const float* mask = (const float*)d_in[1];  // (N,)
  const float* cb   = (const float*)d_in[2];  // (K, 256)
  const int N = in_sizes[1];                  // 32768
  const int D = 256;
  const int K = in_sizes[2] / D;              // 1024

  float* ws    = (float*)d_ws;
  float* acc2  = ws;                          // [0]=loss sum, [1]=n_valid
  float* ee    = ws + 8;                      // K floats
  float* pbest = ws + 8 + K;                  // 2N floats
  int*   pidx  = (int*)(pbest + 2 * (size_t)N); // 2N ints

  float* out_q      = (float*)d_out;          // N*D floats
  float* out_loss   = out_q + (size_t)N * D;  // 1 float
  float* out_idx_f  = out_loss + 1;           // N floats

  hipMemsetAsync(acc2, 0, 2 * sizeof(float), stream);
  vq_code_norms<<<(K + 3) / 4, 256, 0, stream>>>(cb, ee, K);
  vq_argmin<<<(N / 128) * 2, 256, 0, stream>>>(z, cb, ee, pbest, pidx, K);
  vq_finalize<<<N / 128, 256, 0, stream>>>(z, cb, mask, pbest, pidx, out_q, out_idx_f, acc2);
  vq_loss_final<<<1, 64, 0, stream>>>(acc2, out_loss);
}

// Round 3
// 336.971 us; speedup vs baseline: 1.1320x; 1.0189x over previous
//
#include <hip/hip_runtime.h>
#include <cstdint>

#define FLT_MAX_ 3.402823466e+38f

typedef float v2f __attribute__((ext_vector_type(2)));
typedef float v4f __attribute__((ext_vector_type(4)));

// LDS row pitch: 64 floats + 4 pad. Removes XOR swizzle (addresses affine in q
// -> immediate ds_read offsets, no per-q VALU) at max 2-way bank aliasing (free).
#define PITCH 68

// ---------------------------------------------------------------------------
// Pass 0: codebook squared norms ee[k] = ||cb_k||^2   (K=1024, D=256)
// ---------------------------------------------------------------------------
__global__ __launch_bounds__(256) void vq_code_norms(const float* __restrict__ cb,
                                                     float* __restrict__ ee, int K) {
  int wave = threadIdx.x >> 6, lane = threadIdx.x & 63;
  int k = blockIdx.x * 4 + wave;
  if (k >= K) return;
  float4 v = *reinterpret_cast<const float4*>(cb + (size_t)k * 256 + lane * 4);
  float s = v.x * v.x + v.y * v.y + v.z * v.z + v.w * v.w;
  #pragma unroll
  for (int off = 32; off; off >>= 1) s += __shfl_down(s, off, 64);
  if (lane == 0) ee[k] = s;
}

// ---------------------------------------------------------------------------
// Pass 1: fused distance-GEMM + argmin, K-split x2 (512 blocks -> 2 blocks/CU).
// score = ||e||^2 - 2 z.e. Inner loop uses packed fp32 (v_pk_fma_f32, 2 FMA/
// lane/instr -> 314 TF ceiling). LDS rows padded to 68 floats: compute-loop
// addresses are affine in q (immediate offsets), <=2-way bank alias (free).
// ---------------------------------------------------------------------------
__global__ __launch_bounds__(256, 2) void vq_argmin(
    const float* __restrict__ z, const float* __restrict__ cb,
    const float* __restrict__ ee, float* __restrict__ pbest,
    int* __restrict__ pidx, int K) {
  __shared__ float zs[128 * PITCH];
  __shared__ float cs[128 * PITCH];
  const int t = threadIdx.x;
  const int tx = t & 15, ty = t >> 4;
  const int m0 = (blockIdx.x >> 1) * 128;
  const int half = blockIdx.x & 1;
  const int kbase = half * (K >> 1);

  float best[8];
  int bidx[8];
  #pragma unroll
  for (int i = 0; i < 8; ++i) { best[i] = FLT_MAX_; bidx[i] = 0; }

  const int srow = t >> 4, sq = t & 15;   // staging row-base / float4 slot
  const int nkc = K >> 8;                 // 128-code chunks within this half
  for (int kc = 0; kc < nkc; ++kc) {
    v2f acc[8][8];
    #pragma unroll
    for (int i = 0; i < 8; ++i)
      #pragma unroll
      for (int j = 0; j < 8; ++j) acc[i][j] = (v2f)(0.0f);

    for (int dc = 0; dc < 4; ++dc) {
      __syncthreads();
      #pragma unroll
      for (int i = 0; i < 8; ++i) {
        int row = srow + 16 * i;
        float4 v = *reinterpret_cast<const float4*>(
            z + (size_t)(m0 + row) * 256 + dc * 64 + sq * 4);
        *reinterpret_cast<float4*>(&zs[row * PITCH + sq * 4]) = v;
        float4 w = *reinterpret_cast<const float4*>(
            cb + (size_t)(kbase + kc * 128 + row) * 256 + dc * 64 + sq * 4);
        *reinterpret_cast<float4*>(&cs[row * PITCH + sq * 4]) = w;
      }
      __syncthreads();
      #pragma unroll 2
      for (int q = 0; q < 16; ++q) {
        v4f za[8], ca[8];
        #pragma unroll
        for (int i = 0; i < 8; ++i)
          za[i] = *reinterpret_cast<const v4f*>(&zs[(ty + 16 * i) * PITCH + q * 4]);
        #pragma unroll
        for (int j = 0; j < 8; ++j)
          ca[j] = *reinterpret_cast<const v4f*>(&cs[(tx + 16 * j) * PITCH + q * 4]);
        #pragma unroll
        for (int i = 0; i < 8; ++i) {
          #pragma unroll
          for (int j = 0; j < 8; ++j) {
            acc[i][j] = __builtin_elementwise_fma(za[i].xy, ca[j].xy, acc[i][j]);
            acc[i][j] = __builtin_elementwise_fma(za[i].zw, ca[j].zw, acc[i][j]);
          }
        }
      }
    }
    #pragma unroll
    for (int j = 0; j < 8; ++j) {
      int k = kbase + (kc << 7) + tx + 16 * j;
      float e = ee[k];
      #pragma unroll
      for (int i = 0; i < 8; ++i) {
        float s = fmaf(-2.0f, acc[i][j].x + acc[i][j].y, e);
        if (s < best[i] || (s == best[i] && k < bidx[i])) { best[i] = s; bidx[i] = k; }
      }
    }
  }
  #pragma unroll
  for (int off = 8; off; off >>= 1) {
    #pragma unroll
    for (int i = 0; i < 8; ++i) {
      float os = __shfl_xor(best[i], off, 64);
      int   oi = __shfl_xor(bidx[i], off, 64);
      if (os < best[i] || (os == best[i] && oi < bidx[i])) { best[i] = os; bidx[i] = oi; }
    }
  }
  if (tx == 0) {
    #pragma unroll
    for (int i = 0; i < 8; ++i) {
      int n = m0 + ty + 16 * i;
      pbest[2 * n + half] = best[i];
      pidx [2 * n + half] = bidx[i];
    }
  }
}

// ---------------------------------------------------------------------------
// Pass 2: merge K-split partials, gather cb[idx], write quantized = q*m and
// indices (as float), accumulate loss sums; the LAST block to finish computes
// the final loss (saves a 4th launch).
// ---------------------------------------------------------------------------
__global__ __launch_bounds__(256) void vq_finalize(
    const float* __restrict__ z, const float* __restrict__ cb,
    const float* __restrict__ mask, const float* __restrict__ pbest,
    const int* __restrict__ pidx,
    float* __restrict__ out_q, float* __restrict__ out_idx_f,
    float* __restrict__ acc2, int* __restrict__ done_ctr,
    float* __restrict__ out_loss, int nblocks) {
  __shared__ float red[8];
  __shared__ bool last;
  const int lane = threadIdx.x & 63, wave = threadIdx.x >> 6;
  const int base = blockIdx.x * 128;
  float lsum = 0.f, msum = 0.f;
  for (int it = 0; it < 32; ++it) {
    int n = base + it * 4 + wave;
    float m = mask[n];
    float b0 = pbest[2 * n], b1 = pbest[2 * n + 1];
    int k = (b1 < b0) ? pidx[2 * n + 1] : pidx[2 * n];
    float4 zv = *reinterpret_cast<const float4*>(z + (size_t)n * 256 + lane * 4);
    float4 qv = *reinterpret_cast<const float4*>(cb + (size_t)k * 256 + lane * 4);
    float4 o;
    o.x = qv.x * m; o.y = qv.y * m; o.z = qv.z * m; o.w = qv.w * m;
    *reinterpret_cast<float4*>(out_q + (size_t)n * 256 + lane * 4) = o;
    float dx = zv.x - qv.x, dy = zv.y - qv.y, dz = zv.z - qv.z, dw = zv.w - qv.w;
    lsum = fmaf(m, dx * dx + dy * dy + dz * dz + dw * dw, lsum);
    if (lane == 0) {
      msum += m;
      out_idx_f[n] = (m > 0.f) ? (float)k : 0.f;
    }
  }
  #pragma unroll
  for (int off = 32; off; off >>= 1) lsum += __shfl_down(lsum, off, 64);
  if (lane == 0) { red[wave] = lsum; red[4 + wave] = msum; }
  __syncthreads();
  if (threadIdx.x == 0) {
    atomicAdd(&acc2[0], red[0] + red[1] + red[2] + red[3]);
    atomicAdd(&acc2[1], red[4] + red[5] + red[6] + red[7]);
    __threadfence();
    int prev = atomicAdd(done_ctr, 1);
    last = (prev == nblocks - 1);
  }
  __syncthreads();
  if (last && threadIdx.x == 0) {
    float s  = atomicAdd(&acc2[0], 0.0f);  // atomic read -> coherent
    float nv = atomicAdd(&acc2[1], 0.0f);
    out_loss[0] = (nv > 0.f) ? (0.25f * s / (nv * 256.0f)) : 0.0f;
  }
}

// ---------------------------------------------------------------------------
extern "C" void kernel_launch(void* const* d_in, const int* in_sizes, int n_in,
                              void* d_out, int out_size, void* d_ws, size_t ws_size,
                              hipStream_t stream) {
  const float* z    = (const float*)d_in[0];  // (N, 256)
  const float* mask = (const float*)d_in[1];  // (N,)
  const float* cb   = (const float*)d_in[2];  // (K, 256)
  const int N = in_sizes[1];                  // 32768
  const int D = 256;
  const int K = in_sizes[2] / D;              // 1024

  float* ws    = (float*)d_ws;
  float* acc2  = ws;                          // [0]=loss sum, [1]=n_valid
  int*   dctr  = (int*)(ws + 2);              // done counter
  float* ee    = ws + 8;                      // K floats
  float* pbest = ws + 8 + K;                  // 2N floats
  int*   pidx  = (int*)(pbest + 2 * (size_t)N); // 2N ints

  float* out_q      = (float*)d_out;          // N*D floats
  float* out_loss   = out_q + (size_t)N * D;  // 1 float
  float* out_idx_f  = out_loss + 1;           // N floats

  hipMemsetAsync(ws, 0, 3 * sizeof(float), stream);
  vq_code_norms<<<(K + 3) / 4, 256, 0, stream>>>(cb, ee, K);
  vq_argmin<<<(N / 128) * 2, 256, 0, stream>>>(z, cb, ee, pbest, pidx, K);
  vq_finalize<<<N / 128, 256, 0, stream>>>(z, cb, mask, pbest, pidx, out_q,
                                           out_idx_f, acc2, dctr, out_loss, N / 128);
}

// Round 4
// 215.540 us; speedup vs baseline: 1.7697x; 1.5634x over previous
//
#include <hip/hip_runtime.h>
#include <cstdint>

typedef short bf16x8 __attribute__((ext_vector_type(8)));
typedef float f32x4  __attribute__((ext_vector_type(4)));

#define TOK   64      // tokens per block
#define CHUNK 64      // codes per chunk
#define PITCH 264     // ushorts per LDS row (256 data + 8 pad -> 2-way bank alias max)
#define MAXC  24      // candidate cap per token

// round-to-nearest-even float -> bf16 bits
__device__ __forceinline__ unsigned short f2bf(float f) {
  unsigned u = __float_as_uint(f);
  return (unsigned short)((u + 0x7FFFu + ((u >> 16) & 1u)) >> 16);
}

// ---------------------------------------------------------------------------
// Prep: ee[k] = ||cb_k||^2 (fp32) and cb_bf = bf16(cb), row-major [K][256].
// ---------------------------------------------------------------------------
__global__ __launch_bounds__(256) void vq_prep(const float* __restrict__ cb,
                                               unsigned short* __restrict__ cb_bf,
                                               float* __restrict__ ee, int K) {
  int wave = threadIdx.x >> 6, lane = threadIdx.x & 63;
  int k = blockIdx.x * 4 + wave;
  if (k >= K) return;
  float4 v = *reinterpret_cast<const float4*>(cb + (size_t)k * 256 + lane * 4);
  float s = v.x * v.x + v.y * v.y + v.z * v.z + v.w * v.w;
  #pragma unroll
  for (int off = 32; off; off >>= 1) s += __shfl_down(s, off, 64);
  ushort4 b;
  b.x = f2bf(v.x); b.y = f2bf(v.y); b.z = f2bf(v.z); b.w = f2bf(v.w);
  *reinterpret_cast<ushort4*>(cb_bf + (size_t)k * 256 + lane * 4) = b;
  if (lane == 0) ee[k] = s;
}

// ---------------------------------------------------------------------------
// Main: bf16-MFMA screen (d~ = ||e||^2 - 2 z.e) + candidate collection + exact
// fp32 rescore + full epilogue (quantized, indices, loss), one kernel.
// Block = 256 thr (4 waves) = 64 tokens. Wave w owns tokens [16w,16w+16).
// Per chunk: 64 codes, MFMA 16x16x32 over D=256 (8 k-steps x 4 col-tiles).
// C layout (m89-verified): token = (lane>>4)*4 + reg, code = ct*16 + (lane&15).
// ---------------------------------------------------------------------------
__global__ __launch_bounds__(256, 2) void vq_main(
    const float* __restrict__ z, const float* __restrict__ cb,
    const unsigned short* __restrict__ cb_bf, const float* __restrict__ ee,
    const float* __restrict__ mask,
    float* __restrict__ out_q, float* __restrict__ out_idx_f,
    float* __restrict__ out_loss, float* __restrict__ acc2,
    int* __restrict__ done_ctr, int nblocks, int K) {
  __shared__ unsigned short zbf[TOK * PITCH];    // 33792 B
  __shared__ unsigned short cbs[CHUNK * PITCH];  // 33792 B
  __shared__ float znorm[TOK];
  __shared__ int   ccnt[TOK];
  __shared__ int   cand[TOK * MAXC];             // 6144 B
  __shared__ float red[8];
  __shared__ bool  last;

  const int t = threadIdx.x;
  const int n0 = blockIdx.x * TOK;

  // ---- stage z -> bf16 LDS, compute ||z|| ----
  {
    int row = t >> 2, seg = t & 3;  // 4 threads/row, 64 floats each
    const float* zr = z + (size_t)(n0 + row) * 256 + seg * 64;
    float nrm = 0.f;
    #pragma unroll
    for (int i = 0; i < 16; ++i) {
      float4 v = *reinterpret_cast<const float4*>(zr + i * 4);
      nrm += v.x * v.x + v.y * v.y + v.z * v.z + v.w * v.w;
      ushort4 b;
      b.x = f2bf(v.x); b.y = f2bf(v.y); b.z = f2bf(v.z); b.w = f2bf(v.w);
      *reinterpret_cast<ushort4*>(&zbf[row * PITCH + seg * 64 + i * 4]) = b;
    }
    nrm += __shfl_xor(nrm, 1, 64);
    nrm += __shfl_xor(nrm, 2, 64);
    if (seg == 0) { znorm[row] = sqrtf(nrm); ccnt[row] = 0; }
  }
  __syncthreads();

  const int wv = t >> 6, lane = t & 63;
  const int quad = lane >> 4, l15 = lane & 15;

  float amin_reg[4];  // running screened min per reg-row (token = wv*16+quad*4+r)
  #pragma unroll
  for (int r = 0; r < 4; ++r) amin_reg[r] = 3.4e38f;

  const int nch = K / CHUNK;
  for (int ch = 0; ch < nch; ++ch) {
    const int kbase = ch * CHUNK;
    __syncthreads();  // protect cbs readers of previous chunk
    {   // stage cb_bf chunk: 64 rows x 512 B
      int row = t >> 2, seg = t & 3;  // 4 thr/row, 128 B each
      const unsigned short* src = cb_bf + (size_t)(kbase + row) * 256 + seg * 64;
      #pragma unroll
      for (int i = 0; i < 8; ++i) {
        uint4 v = *reinterpret_cast<const uint4*>(src + i * 8);
        *reinterpret_cast<uint4*>(&cbs[row * PITCH + seg * 64 + i * 8]) = v;
      }
    }
    __syncthreads();

    f32x4 a0 = {0.f,0.f,0.f,0.f}, a1 = {0.f,0.f,0.f,0.f};
    f32x4 a2 = {0.f,0.f,0.f,0.f}, a3 = {0.f,0.f,0.f,0.f};
    const unsigned short* za = &zbf[(wv * 16 + l15) * PITCH + quad * 8];
    const unsigned short* cbase = &cbs[l15 * PITCH + quad * 8];
    #pragma unroll
    for (int kk = 0; kk < 8; ++kk) {
      bf16x8 a  = *reinterpret_cast<const bf16x8*>(za + kk * 32);
      bf16x8 b0 = *reinterpret_cast<const bf16x8*>(cbase + kk * 32);
      bf16x8 b1 = *reinterpret_cast<const bf16x8*>(cbase + 16 * PITCH + kk * 32);
      bf16x8 b2 = *reinterpret_cast<const bf16x8*>(cbase + 32 * PITCH + kk * 32);
      bf16x8 b3 = *reinterpret_cast<const bf16x8*>(cbase + 48 * PITCH + kk * 32);
      a0 = __builtin_amdgcn_mfma_f32_16x16x32_bf16(a, b0, a0, 0, 0, 0);
      a1 = __builtin_amdgcn_mfma_f32_16x16x32_bf16(a, b1, a1, 0, 0, 0);
      a2 = __builtin_amdgcn_mfma_f32_16x16x32_bf16(a, b2, a2, 0, 0, 0);
      a3 = __builtin_amdgcn_mfma_f32_16x16x32_bf16(a, b3, a3, 0, 0, 0);
    }

    // screened distances + running min + gated candidate append
    float e0 = ee[kbase + l15],      e1 = ee[kbase + 16 + l15];
    float e2 = ee[kbase + 32 + l15], e3 = ee[kbase + 48 + l15];
    float en0 = sqrtf(e0), en1 = sqrtf(e1), en2 = sqrtf(e2), en3 = sqrtf(e3);
    #pragma unroll
    for (int r = 0; r < 4; ++r) {
      float d0 = e0 - 2.f * a0[r];
      float d1 = e1 - 2.f * a1[r];
      float d2 = e2 - 2.f * a2[r];
      float d3 = e3 - 2.f * a3[r];
      float w = fminf(fminf(d0, d1), fminf(d2, d3));
      #pragma unroll
      for (int off = 1; off < 16; off <<= 1) w = fminf(w, __shfl_xor(w, off, 64));
      float am = fminf(amin_reg[r], w);
      amin_reg[r] = am;
      int tok = wv * 16 + quad * 4 + r;
      float zn = znorm[tok];
      // margin covers 2-sided screen error (~10 sigma) + scale term
      if (d0 <= am + 1.5f + 0.002f * zn * en0) {
        int s = atomicAdd(&ccnt[tok], 1);
        if (s < MAXC) cand[tok * MAXC + s] = kbase + l15;
      }
      if (d1 <= am + 1.5f + 0.002f * zn * en1) {
        int s = atomicAdd(&ccnt[tok], 1);
        if (s < MAXC) cand[tok * MAXC + s] = kbase + 16 + l15;
      }
      if (d2 <= am + 1.5f + 0.002f * zn * en2) {
        int s = atomicAdd(&ccnt[tok], 1);
        if (s < MAXC) cand[tok * MAXC + s] = kbase + 32 + l15;
      }
      if (d3 <= am + 1.5f + 0.002f * zn * en3) {
        int s = atomicAdd(&ccnt[tok], 1);
        if (s < MAXC) cand[tok * MAXC + s] = kbase + 48 + l15;
      }
    }
  }
  __syncthreads();

  // ---- exact fp32 rescore + epilogue: wave per token ----
  float lsum = 0.f, msum = 0.f;
  for (int it = 0; it < TOK / 4; ++it) {
    int tok = it * 4 + wv;
    int n = n0 + tok;
    float4 zv = *reinterpret_cast<const float4*>(z + (size_t)n * 256 + lane * 4);
    int cnt = min(ccnt[tok], MAXC);
    float bs = 3.4e38f; int bk = 0;
    for (int c = 0; c < cnt; ++c) {
      int k = cand[tok * MAXC + c];
      float4 ev = *reinterpret_cast<const float4*>(cb + (size_t)k * 256 + lane * 4);
      float dp = zv.x * ev.x + zv.y * ev.y + zv.z * ev.z + zv.w * ev.w;
      #pragma unroll
      for (int off = 32; off; off >>= 1) dp += __shfl_xor(dp, off, 64);
      float s = ee[k] - 2.f * dp;           // exact fp32 score (same for all lanes)
      if (s < bs || (s == bs && k < bk)) { bs = s; bk = k; }
    }
    float m = mask[n];
    float4 qv = *reinterpret_cast<const float4*>(cb + (size_t)bk * 256 + lane * 4);
    float4 o; o.x = qv.x * m; o.y = qv.y * m; o.z = qv.z * m; o.w = qv.w * m;
    *reinterpret_cast<float4*>(out_q + (size_t)n * 256 + lane * 4) = o;
    float dx = zv.x - qv.x, dy = zv.y - qv.y, dz = zv.z - qv.z, dw = zv.w - qv.w;
    lsum = fmaf(m, dx * dx + dy * dy + dz * dz + dw * dw, lsum);
    if (lane == 0) {
      msum += m;
      out_idx_f[n] = (m > 0.f) ? (float)bk : 0.f;
    }
  }
  #pragma unroll
  for (int off = 32; off; off >>= 1) lsum += __shfl_down(lsum, off, 64);
  if (lane == 0) { red[wv] = lsum; red[4 + wv] = msum; }
  __syncthreads();
  if (t == 0) {
    atomicAdd(&acc2[0], red[0] + red[1] + red[2] + red[3]);
    atomicAdd(&acc2[1], red[4] + red[5] + red[6] + red[7]);
    __threadfence();
    int prev = atomicAdd(done_ctr, 1);
    last = (prev == nblocks - 1);
  }
  __syncthreads();
  if (last && t == 0) {
    float s  = atomicAdd(&acc2[0], 0.0f);
    float nv = atomicAdd(&acc2[1], 0.0f);
    out_loss[0] = (nv > 0.f) ? (0.25f * s / (nv * 256.0f)) : 0.0f;
  }
}

// ---------------------------------------------------------------------------
extern "C" void kernel_launch(void* const* d_in, const int* in_sizes, int n_in,
                              void* d_out, int out_size, void* d_ws, size_t ws_size,
                              hipStream_t stream) {
  const float* z    = (const float*)d_in[0];  // (N, 256)
  const float* mask = (const float*)d_in[1];  // (N,)
  const float* cb   = (const float*)d_in[2];  // (K, 256)
  const int N = in_sizes[1];                  // 32768
  const int D = 256;
  const int K = in_sizes[2] / D;              // 1024

  float* wsf   = (float*)d_ws;
  float* acc2  = wsf;                          // 2 floats
  int*   dctr  = (int*)(wsf + 2);              // 1 int
  float* ee    = wsf + 8;                      // K floats
  unsigned short* cb_bf = (unsigned short*)(wsf + 8 + K);  // K*256 bf16

  float* out_q     = (float*)d_out;            // N*D
  float* out_loss  = out_q + (size_t)N * D;    // 1
  float* out_idx_f = out_loss + 1;             // N

  hipMemsetAsync(wsf, 0, 12, stream);
  vq_prep<<<(K + 3) / 4, 256, 0, stream>>>(cb, cb_bf, ee, K);
  vq_main<<<N / TOK, 256, 0, stream>>>(z, cb, cb_bf, ee, mask, out_q, out_idx_f,
                                       out_loss, acc2, dctr, N / TOK, K);
}